// Round 2
// baseline (334.153 us; speedup 1.0000x reference)
//
#include <hip/hip_runtime.h>

#define HH 1024
#define INW 512
#define BB 32
#define BG 16            // batches per block (B split across 2 blocks per row)
#define Z_MIN_C 0.001f
#define Z_RANGE_C 0.099f
#define E_H_C 0.5f

__device__ __forceinline__ float sigmoidf_(float v) {
    return 1.0f / (1.0f + __expf(-v));
}

// Grid: 2048 blocks = (j = bid>>1) x (batch-group g = bid&1).
// Each block: row j, batches b in [g*16, g*16+16), 256 threads x 4 consecutive k.
// Per-(j,k) params computed once per block; 16 per-b accumulators in registers;
// all cross-lane reductions deferred to after the streaming loop.
__global__ __launch_bounds__(256) void stp_fused(
    const float* __restrict__ x,    // (IN, B)
    const float* __restrict__ h,    // (B, H)
    const float* __restrict__ X,    // (B, H, H)
    const float* __restrict__ U,    // (B, H, H)
    const float* __restrict__ c_x,  // (H, H)
    const float* __restrict__ c_u,  // (H, H)
    const float* __restrict__ c_U,  // (H, H)
    const float* __restrict__ c_h,  // (H, 1)
    const float* __restrict__ w,    // (H, H)
    const float* __restrict__ p,    // (H, IN)
    const float* __restrict__ bias, // (H, 1)
    float* __restrict__ out)        // (B, H)
{
    const int j = blockIdx.x >> 1;
    const int g = blockIdx.x & 1;
    const int t = threadIdx.x;
    const int lane = t & 63;
    const int wave = t >> 6;

    __shared__ float px_part[16][BG];   // p@x partials: seg x b_local
    __shared__ float rec_part[BG][4];   // rec partials: b_local x wave

    // ---- fused p@x prologue: 16 segs x 16 batches, each seg covers 32 inputs ----
    {
        const int b_id = t & 15;
        const int seg = t >> 4;
        float acc = 0.0f;
        const float* prow = p + j * INW + seg * 32;
        const float* xcol = x + seg * 32 * BB + (g * BG + b_id);
        #pragma unroll
        for (int i = 0; i < 32; ++i)
            acc = fmaf(prow[i], xcol[i * BB], acc);
        px_part[seg][b_id] = acc;
    }

    // ---- per-k parameters for row j (computed once, reused over 16 batches) ----
    const int k0 = t * 4;
    float4 cx4 = *(const float4*)(c_x + j * HH + k0);
    float4 cu4 = *(const float4*)(c_u + j * HH + k0);
    float4 cC4 = *(const float4*)(c_U + j * HH + k0);
    float4 wv4 = *(const float4*)(w + j * HH + k0);
    const float* cxv = &cx4.x;
    const float* cuv = &cu4.x;
    const float* cCv = &cC4.x;
    const float* wvv = &wv4.x;

    float zx[4], ozx[4], Acoef[4], ozu[4], Uc[4], wr[4];
    #pragma unroll
    for (int c = 0; c < 4; ++c) {
        float zxx = Z_MIN_C + Z_RANGE_C * sigmoidf_(cxv[c]);
        float zuu = Z_MIN_C + Z_RANGE_C * sigmoidf_(cuv[c]);
        float ucc = 0.9f * sigmoidf_(cCv[c]);
        zx[c] = zxx;
        ozx[c] = 1.0f - zxx;
        ozu[c] = 1.0f - zuu;
        Uc[c] = ucc;
        Acoef[c] = ucc * zuu;
        wr[c] = wvv[c];
    }

    // ---- streaming loop: 16 batches, unroll 4 => 8 X/U float4 loads in flight ----
    float s[BG];
    #pragma unroll
    for (int i = 0; i < BG; ++i) s[i] = 0.0f;

    for (int bb = 0; bb < BG; bb += 4) {
        float4 Xl[4], Ul[4], hk[4];
        float hj[4];
        #pragma unroll
        for (int i = 0; i < 4; ++i) {
            const int b = g * BG + bb + i;
            const int rowbase = (b * HH + j) * HH;
            Xl[i] = *(const float4*)(X + rowbase + k0);
            Ul[i] = *(const float4*)(U + rowbase + k0);
            hk[i] = *(const float4*)(h + b * HH + k0);
            hj[i] = h[b * HH + j];   // block-uniform -> scalar load
        }
        #pragma unroll
        for (int i = 0; i < 4; ++i) {
            const float hjv = hj[i];
            const float* Xv = &Xl[i].x;
            const float* Uv = &Ul[i].x;
            const float* hkv = &hk[i].x;
            float ss = 0.0f;
            #pragma unroll
            for (int c = 0; c < 4; ++c) {
                // X_new = z_x + (1-z_x)*X - U*(X*hj)
                float Xn = fmaf(ozx[c], Xv[c], zx[c]);
                Xn = fmaf(-Uv[c], Xv[c] * hjv, Xn);
                // U_new = Ucap*z_u + (1-z_u)*U + Ucap*hj*(1-U), clamp [Ucap, 1]
                float Un = fmaf(ozu[c], Uv[c], Acoef[c]);
                Un = fmaf(Uc[c] * hjv, 1.0f - Uv[c], Un);
                Un = fminf(fmaxf(Un, Uc[c]), 1.0f);
                // rec contribution: w*U_new*X_new * h[b,k]
                ss = fmaf(wr[c] * hkv[c], Un * Xn, ss);
            }
            s[bb + i] += ss;
        }
    }

    // ---- deferred reductions: 16 values x wave shuffle, once ----
    #pragma unroll
    for (int i = 0; i < BG; ++i) {
        float v = s[i];
        #pragma unroll
        for (int off = 32; off > 0; off >>= 1)
            v += __shfl_xor(v, off);
        if (lane == 0) rec_part[i][wave] = v;
    }
    __syncthreads();

    // ---- finalize: thread t = local batch ----
    if (t < BG) {
        const int b = g * BG + t;
        float rec = rec_part[t][0] + rec_part[t][1] + rec_part[t][2] + rec_part[t][3];
        float px = 0.0f;
        #pragma unroll
        for (int sgi = 0; sgi < 16; ++sgi) px += px_part[sgi][t];
        float pre = rec + px + bias[j];
        float zh = E_H_C * sigmoidf_(c_h[j]);
        float hv = h[b * HH + j];
        out[b * HH + j] = (1.0f - zh) * hv + zh * sigmoidf_(pre);
    }
}

extern "C" void kernel_launch(void* const* d_in, const int* in_sizes, int n_in,
                              void* d_out, int out_size, void* d_ws, size_t ws_size,
                              hipStream_t stream) {
    const float* x   = (const float*)d_in[0];
    const float* h   = (const float*)d_in[1];
    const float* X   = (const float*)d_in[2];
    const float* U   = (const float*)d_in[3];
    const float* c_x = (const float*)d_in[4];
    const float* c_u = (const float*)d_in[5];
    const float* c_U = (const float*)d_in[6];
    const float* c_h = (const float*)d_in[7];
    const float* w   = (const float*)d_in[8];
    const float* p   = (const float*)d_in[9];
    const float* b   = (const float*)d_in[10];
    float* out = (float*)d_out;

    stp_fused<<<HH * 2, 256, 0, stream>>>(x, h, X, U, c_x, c_u, c_U, c_h, w, p, b, out);
}

// Round 3
// 291.600 us; speedup vs baseline: 1.1459x; 1.1459x over previous
//
#include <hip/hip_runtime.h>

#define HH 1024
#define INW 512
#define BB 32
#define BG 8             // batches per block: B=32 split across 4 blocks per row
#define Z_MIN_C 0.001f
#define Z_RANGE_C 0.099f
#define E_H_C 0.5f

typedef float v4f __attribute__((ext_vector_type(4)));

__device__ __forceinline__ float sigmoidf_(float v) {
    return 1.0f / (1.0f + __expf(-v));
}

// Grid: 4096 blocks. j = bid & 1023, g = bid >> 10 (g in [0,4)).
// 4096 % 8 alignment => all 4 g-blocks of row j land on the same XCD =>
// c_x/c_u/c_U/w row j is L2-resident after first touch (2 MB/XCD working set).
// Each block: row j, batches b in [g*8, g*8+8), 256 threads x 4 consecutive k.
// Depth-3 rotating register prefetch keeps ~6 KB/wave posted to the memory
// system at all times (the R1/R2 lesson: BW ~ waves/CU x bytes-in-flight/wave).
__global__ __launch_bounds__(256, 4) void stp_fused(
    const float* __restrict__ x,    // (IN, B)
    const float* __restrict__ h,    // (B, H)
    const float* __restrict__ X,    // (B, H, H)
    const float* __restrict__ U,    // (B, H, H)
    const float* __restrict__ c_x,  // (H, H)
    const float* __restrict__ c_u,  // (H, H)
    const float* __restrict__ c_U,  // (H, H)
    const float* __restrict__ c_h,  // (H, 1)
    const float* __restrict__ w,    // (H, H)
    const float* __restrict__ p,    // (H, IN)
    const float* __restrict__ bias, // (H, 1)
    float* __restrict__ out)        // (B, H)
{
    const int j = blockIdx.x & (HH - 1);
    const int g = blockIdx.x >> 10;
    const int t = threadIdx.x;
    const int lane = t & 63;
    const int wave = t >> 6;

    __shared__ float px_part[32][BG];   // p@x partials: seg x b_local
    __shared__ float rec_part[BG][4];   // rec partials: b_local x wave

    // ---- fused p@x prologue: 32 segs x 8 batches, 16 inputs per seg ----
    {
        const int b_id = t & 7;
        const int seg = t >> 3;                 // 0..31
        const int b = g * BG + b_id;
        float acc = 0.0f;
        const float* prow = p + j * INW + seg * 16;
        const float* xcol = x + (seg * 16) * BB + b;
        #pragma unroll
        for (int i = 0; i < 16; ++i)
            acc = fmaf(prow[i], xcol[i * BB], acc);
        px_part[seg][b_id] = acc;
    }

    // ---- per-k parameters for row j (once per block, reused over 8 batches) ----
    const int k0 = t * 4;
    v4f cx4 = *(const v4f*)(c_x + j * HH + k0);
    v4f cu4 = *(const v4f*)(c_u + j * HH + k0);
    v4f cC4 = *(const v4f*)(c_U + j * HH + k0);
    v4f wv4 = *(const v4f*)(w + j * HH + k0);

    float zx[4], ozx[4], Acoef[4], ozu[4], Ucap[4], wr[4];
    #pragma unroll
    for (int c = 0; c < 4; ++c) {
        float zxx = Z_MIN_C + Z_RANGE_C * sigmoidf_(cx4[c]);
        float zuu = Z_MIN_C + Z_RANGE_C * sigmoidf_(cu4[c]);
        float ucc = 0.9f * sigmoidf_(cC4[c]);
        zx[c] = zxx;
        ozx[c] = 1.0f - zxx;
        ozu[c] = 1.0f - zuu;
        Ucap[c] = ucc;
        Acoef[c] = ucc * zuu;
        wr[c] = wv4[c];
    }

    // ---- streaming loop over 8 batches, depth-3 rotating prefetch ----
    float s[BG];
    v4f Xb[3], Ub[3], hb[3];
    float hjb[3];

    #pragma unroll
    for (int i = 0; i < 3; ++i) {
        const int b = g * BG + i;
        const int rb = (b * HH + j) * HH + k0;
        Xb[i] = __builtin_nontemporal_load((const v4f*)(X + rb));
        Ub[i] = __builtin_nontemporal_load((const v4f*)(U + rb));
        hb[i] = *(const v4f*)(h + b * HH + k0);
        hjb[i] = h[b * HH + j];
    }

    #pragma unroll
    for (int i = 0; i < BG; ++i) {
        const int sl = i % 3;
        // pull current iteration's data into temps, then immediately re-issue
        // the slot's loads for iteration i+3 (keeps loads posted during compute)
        v4f Xc = Xb[sl];
        v4f Uc = Ub[sl];
        v4f hc = hb[sl];
        float hjv = hjb[sl];
        if (i + 3 < BG) {
            const int b = g * BG + i + 3;
            const int rb = (b * HH + j) * HH + k0;
            Xb[sl] = __builtin_nontemporal_load((const v4f*)(X + rb));
            Ub[sl] = __builtin_nontemporal_load((const v4f*)(U + rb));
            hb[sl] = *(const v4f*)(h + b * HH + k0);
            hjb[sl] = h[b * HH + j];
        }
        float ss = 0.0f;
        #pragma unroll
        for (int c = 0; c < 4; ++c) {
            // X_new = z_x + (1-z_x)*X - U*(X*hj)
            float Xn = fmaf(ozx[c], Xc[c], zx[c]);
            Xn = fmaf(-Uc[c], Xc[c] * hjv, Xn);
            // U_new = Ucap*z_u + (1-z_u)*U + Ucap*hj*(1-U), clamp [Ucap, 1]
            float Un = fmaf(ozu[c], Uc[c], Acoef[c]);
            Un = fmaf(Ucap[c] * hjv, 1.0f - Uc[c], Un);
            Un = fminf(fmaxf(Un, Ucap[c]), 1.0f);
            // rec contribution: w*U_new*X_new * h[b,k]
            ss = fmaf(wr[c] * hc[c], Un * Xn, ss);
        }
        s[i] = ss;
    }

    // ---- deferred cross-lane reductions (8 independent shuffle chains) ----
    #pragma unroll
    for (int i = 0; i < BG; ++i) {
        float v = s[i];
        #pragma unroll
        for (int off = 32; off > 0; off >>= 1)
            v += __shfl_xor(v, off);
        if (lane == 0) rec_part[i][wave] = v;
    }
    __syncthreads();

    // ---- finalize: thread t = local batch ----
    if (t < BG) {
        const int b = g * BG + t;
        float rec = rec_part[t][0] + rec_part[t][1] + rec_part[t][2] + rec_part[t][3];
        float px = 0.0f;
        #pragma unroll
        for (int sgi = 0; sgi < 32; ++sgi) px += px_part[sgi][t];
        float pre = rec + px + bias[j];
        float zh = E_H_C * sigmoidf_(c_h[j]);
        float hv = h[b * HH + j];
        out[b * HH + j] = (1.0f - zh) * hv + zh * sigmoidf_(pre);
    }
}

extern "C" void kernel_launch(void* const* d_in, const int* in_sizes, int n_in,
                              void* d_out, int out_size, void* d_ws, size_t ws_size,
                              hipStream_t stream) {
    const float* x   = (const float*)d_in[0];
    const float* h   = (const float*)d_in[1];
    const float* X   = (const float*)d_in[2];
    const float* U   = (const float*)d_in[3];
    const float* c_x = (const float*)d_in[4];
    const float* c_u = (const float*)d_in[5];
    const float* c_U = (const float*)d_in[6];
    const float* c_h = (const float*)d_in[7];
    const float* w   = (const float*)d_in[8];
    const float* p   = (const float*)d_in[9];
    const float* b   = (const float*)d_in[10];
    float* out = (float*)d_out;

    stp_fused<<<HH * 4, 256, 0, stream>>>(x, h, X, U, c_x, c_u, c_U, c_h, w, p, b, out);
}